// Round 13
// baseline (189.066 us; speedup 1.0000x reference)
//
#include <hip/hip_runtime.h>

#define BATCH 16
#define CH    64
#define TLEN  200
#define NP    30
#define HID   128
#define NSEQ  (BATCH * NP)   // 480
#define HP    144            // hz (f16) row pitch in halves (288 B)
#define H8P   160            // hz8 (fp8) row pitch in bytes
#define XP    72             // xlds per-seq row pitch in halves (144 B)
#define XGW   520            // xgb row pitch in floats (2080 B)

typedef _Float16 half8 __attribute__((ext_vector_type(8)));
typedef float    f32x4 __attribute__((ext_vector_type(4)));
typedef int      i32x8 __attribute__((ext_vector_type(8)));
typedef unsigned char u8;

// NaN/Inf-safe, clamp-free: exp->inf degrades gracefully through rcp.
__device__ __forceinline__ float sigm_fast(float x) {
    return __builtin_amdgcn_rcpf(1.0f + __expf(-x));
}
__device__ __forceinline__ float tanh_fast(float x) {
    return 1.0f - 2.0f * __builtin_amdgcn_rcpf(__expf(2.0f * x) + 1.0f);
}
__device__ __forceinline__ half8 cvt8(float4 a, float4 b) {
    return (half8){(_Float16)a.x,(_Float16)a.y,(_Float16)a.z,(_Float16)a.w,
                   (_Float16)b.x,(_Float16)b.y,(_Float16)b.z,(_Float16)b.w};
}

#define MFMA16(A,B,C) __builtin_amdgcn_mfma_f32_16x16x32_f16((A),(B),(C),0,0,0)
// K=128-in-one-instruction scaled MFMA; fmt 0 = fp8 e4m3 (OCP), scale 127 = x1.0
#define MFMA8(A,B,C) __builtin_amdgcn_mfma_scale_f32_16x16x128_f8f6f4((A),(B),(C),0,0,0,127,0,127)

// ---------------------------------------------------------------------------
// Fused LSTM. 240 blocks (XCD-swizzled), 512 threads = 8 waves = 2 waves/SIMD.
// = r9 (best, 125us) with the recurrent GEMM's SIGMOID gates (i,f,o) moved to
// fp8-e4m3 K=128 scaled MFMA (one instruction replaces a 4-chain):
//   per-wave step: 3 fp8 + 4 f16 MFMAs -> per-SIMD issue window 620 -> ~363cy.
//   g-gate (tanh, slope 1) stays f16; sigmoid's <=0.25 slope damps the fp8
//   quantization noise ~4x. h kept dual f16+fp8 in LDS (1 extra byte store).
// Kept from r9: compact h rows + shared zero row (broadcast A-reads), x fully
// LDS-resident (zero VMEM in loop), xg per-period f16 burst in C-layout,
// acc-major order (i,f,g early / o last), act on all lanes, setprio.
// ---------------------------------------------------------------------------
__global__ __launch_bounds__(512, 2) void fused_lstm(
    const float* __restrict__ x, const float* __restrict__ W_ih,
    const float* __restrict__ W_hh, const float* __restrict__ b_ih,
    const float* __restrict__ b_hh, const float* __restrict__ W_fc,
    const float* __restrict__ b_fc, float* __restrict__ out)
{
    const int tid = threadIdx.x;
    const int w  = tid >> 6;     // wave 0..7 -> owns gate sub-cols 16w+lr
    const int l  = tid & 63;
    const int lr = l & 15;
    const int lq = l >> 4;

    // XCD-chunked swizzle: XCD c gets pairs c*30..c*30+29 (= 2 full batches)
    const int blk  = blockIdx.x;
    const int pair = (blk & 7) * 30 + (blk >> 3);
    const int n0 = pair * 2;
    const int b0 = n0 / NP;
    const int p0 = n0 % NP;      // even -> both seqs share b0

    __shared__ __align__(16) _Float16 hz[5][HP];         // f16 h: rows {0,1}buf0,{2,3}buf1,{4}zero
    __shared__ __align__(16) u8       hz8[5][H8P];       // fp8 h: same row scheme
    __shared__ __align__(16) _Float16 xlds[TLEN][2][XP]; // 57600 B; ALL x, f16
    __shared__ __align__(16) float    xgb[2][16 * XGW];  // 66560 B; xg+bias, f32 C-layout

    // ---- W fragments in registers (loaded once) ----
    // fp8 B-frags for i,f,o: lane holds W[col=128T+16w+lr][K=32lq..32lq+31] as 8 dwords
    i32x8 b8i, b8f, b8o;
    {
        const int Ts[3] = {0, 1, 3};
        i32x8* dst[3] = {&b8i, &b8f, &b8o};
#pragma unroll
        for (int q = 0; q < 3; ++q) {
            const float* rw = W_hh + (size_t)(128*Ts[q] + 16*w + lr) * HID + 32*lq;
            i32x8 pk;
#pragma unroll
            for (int r = 0; r < 8; ++r) {
                int v = __builtin_amdgcn_cvt_pk_fp8_f32(rw[4*r],     rw[4*r + 1], 0, false);
                v     = __builtin_amdgcn_cvt_pk_fp8_f32(rw[4*r + 2], rw[4*r + 3], v, true);
                pk[r] = v;
            }
            *dst[q] = pk;
        }
    }
    // f16 B-frags for the g-gate (T=2), K-chunked
    half8 bg16[4];
    {
        const float* rh = W_hh + (size_t)(128*2 + 16*w + lr) * HID;
#pragma unroll
        for (int kt = 0; kt < 4; ++kt) {
            const int k0 = 32*kt + 8*lq;
            bg16[kt] = cvt8(*(const float4*)(rh + k0), *(const float4*)(rh + k0 + 4));
        }
    }
    half8 bih[4][2];   // W_ih f16, gate-type T, K-frag j (K=64)
    float biasx[4];
#pragma unroll
    for (int T = 0; T < 4; ++T) {
        const int g = 128*T + 16*w + lr;
        const float* ri = W_ih + (size_t)g * CH;
#pragma unroll
        for (int j = 0; j < 2; ++j) {
            const int k0 = 32*j + 8*lq;
            bih[T][j] = cvt8(*(const float4*)(ri + k0), *(const float4*)(ri + k0 + 4));
        }
        biasx[T] = b_ih[g] + b_hh[g];
    }

    // zero h buffers (rows 0-3 = h_0 = 0; row 4 = permanent zero row)
    if (tid < (5 * HP) / 2) ((unsigned*)hz)[tid] = 0u;
    if (tid < (5 * H8P) / 4) ((unsigned*)hz8)[tid] = 0u;

    // ---- prologue: stage ALL x for both seqs into LDS (one-time gather).
    for (int e = tid; e < CH * TLEN; e += 512) {
        const int t = e % TLEN, c = e / TLEN;
        const float* src = x + ((size_t)(b0 * CH + c) * TLEN + t) * NP + p0;
        float2 v = *(const float2*)src;
        xlds[t][0][c] = (_Float16)v.x;
        xlds[t][1][c] = (_Float16)v.y;
    }
    float cst = 0.f;                      // c-state: valid in lanes l<32
    const int hcol = 16*w + lr;
    // A-frag source rows: lr==0 -> seq0, lr==4 -> seq1, else shared ZERO row.
    const int r0 = (lr == 0) ? 0 : (lr == 4) ? 1 : 4;   // buf 0
    const int r1 = (lr == 0) ? 2 : (lr == 4) ? 3 : 4;   // buf 1
    const _Float16* hpA  = &hz[r0][8 * lq];
    const _Float16* hpB  = &hz[r1][8 * lq];
    const u8*       hp8A = &hz8[r0][32 * lq];
    const u8*       hp8B = &hz8[r1][32 * lq];
    __syncthreads();                      // h buffers + xlds resident

    // per-period xg GEMM from resident xlds (f16, bias folded, C-layout out)
#define XG_BURST(P, TB) {                                                         \
        const _Float16* xr_ = &xlds[8*(P) + (lr >> 1)][lr & 1][8*lq];             \
        half8 xf0_ = *(const half8*)xr_;                                          \
        half8 xf1_ = *(const half8*)(xr_ + 32);                                   \
        f32x4 g0_ = {biasx[0], biasx[0], biasx[0], biasx[0]};                     \
        f32x4 g1_ = {biasx[1], biasx[1], biasx[1], biasx[1]};                     \
        f32x4 g2_ = {biasx[2], biasx[2], biasx[2], biasx[2]};                     \
        f32x4 g3_ = {biasx[3], biasx[3], biasx[3], biasx[3]};                     \
        g0_ = MFMA16(xf0_, bih[0][0], g0_); g0_ = MFMA16(xf1_, bih[0][1], g0_);   \
        g1_ = MFMA16(xf0_, bih[1][0], g1_); g1_ = MFMA16(xf1_, bih[1][1], g1_);   \
        g2_ = MFMA16(xf0_, bih[2][0], g2_); g2_ = MFMA16(xf1_, bih[2][1], g2_);   \
        g3_ = MFMA16(xf0_, bih[3][0], g3_); g3_ = MFMA16(xf1_, bih[3][1], g3_);   \
        _Pragma("unroll") for (int r_ = 0; r_ < 4; ++r_) {                        \
            float* dst_ = &xgb[TB][(4*lq + r_) * XGW + hcol * 4];                 \
            *(f32x4*)dst_ = (f32x4){g0_[r_], g1_[r_], g2_[r_], g3_[r_]};          \
        } }

    XG_BURST(0, 0)          // xg for period 0
    __syncthreads();

#pragma unroll 1
    for (int p = 0; p < 25; ++p) {
        const int pe = p & 1;
#pragma unroll
        for (int k = 0; k < 8; ++k) {
            const int cur = k & 1;       // t = 8p+k, t&1 = k&1
            const int nxt = cur ^ 1;
            // xg (f32 C-layout quad, row-broadcast b128)
            f32x4 xg4 = *(const f32x4*)&xgb[pe][(2*k + (lq & 1)) * XGW + hcol * 4];
            // A fragments: fp8 (32 B) for i,f,o; f16 chunks for g
            i32x8 a8 = *(const i32x8*)(cur ? hp8B : hp8A);
            const _Float16* hr = cur ? hpB : hpA;
            half8 a0 = *(const half8*)(hr);
            half8 a1 = *(const half8*)(hr + 32);
            half8 a2 = *(const half8*)(hr + 64);
            half8 a3 = *(const half8*)(hr + 96);
            f32x4 zz = {0.f, 0.f, 0.f, 0.f};
            __builtin_amdgcn_s_setprio(1);
            // i,f: one K=128 fp8 MFMA each; g: f16 chain — all complete EARLY
            f32x4 ci = MFMA8(a8, b8i, zz);
            f32x4 cf = MFMA8(a8, b8f, zz);
            f32x4 cg = MFMA16(a0, bg16[0], zz);
            cg = MFMA16(a1, bg16[1], cg);
            cg = MFMA16(a2, bg16[2], cg);
            cg = MFMA16(a3, bg16[3], cg);
            // early act front (all lanes; dead-row lanes produce garbage)
            float si = sigm_fast(ci[0] + xg4[0]);
            float sf = sigm_fast(cf[0] + xg4[1]);
            float tg = tanh_fast(cg[0] + xg4[2]);
            float cnew = sf * cst + si * tg;
            // o-gate LAST (single fp8 MFMA)
            f32x4 co = MFMA8(a8, b8o, zz);
            __builtin_amdgcn_s_setprio(0);
            if (k == 0 && p < 24) XG_BURST(p + 1, pe ^ 1)    // xg for period p+1
            // tail: sigm(go) || tanh(c) -> mul -> cvt -> writes (f16 + fp8)
            float hv = sigm_fast(co[0] + xg4[3]) * tanh_fast(cnew);
            cst = cnew;
            if (l < 32) {
                hz[2*nxt + lq][hcol] = (_Float16)hv;
                int hb = __builtin_amdgcn_cvt_pk_fp8_f32(hv, hv, 0, false);
                hz8[2*nxt + lq][hcol] = (u8)hb;
            }
            __syncthreads();
        }
    }

    // FC epilogue: h_200 in hz rows 0,1 (t=199 wrote nxt=0)
    if (tid < 2 * CH) {
        const int s = tid >> 6, ch = tid & 63;
        const float* wf = W_fc + (size_t)ch * HID;
        float acc = b_fc[ch];
#pragma unroll
        for (int j8 = 0; j8 < 16; ++j8) {
            half8 hv = *(const half8*)&hz[s][8 * j8];
            float4 w0 = *(const float4*)(wf + 8 * j8);
            float4 w1 = *(const float4*)(wf + 8 * j8 + 4);
            acc += w0.x * (float)hv[0] + w0.y * (float)hv[1]
                 + w0.z * (float)hv[2] + w0.w * (float)hv[3]
                 + w1.x * (float)hv[4] + w1.y * (float)hv[5]
                 + w1.z * (float)hv[6] + w1.w * (float)hv[7];
        }
        out[(size_t)(n0 + s) * CH + ch] = acc;
    }
}

extern "C" void kernel_launch(void* const* d_in, const int* in_sizes, int n_in,
                              void* d_out, int out_size, void* d_ws, size_t ws_size,
                              hipStream_t stream) {
    (void)in_sizes; (void)n_in; (void)out_size; (void)d_ws; (void)ws_size;
    fused_lstm<<<NSEQ / 2, 512, 0, stream>>>(
        (const float*)d_in[0], (const float*)d_in[1], (const float*)d_in[2],
        (const float*)d_in[3], (const float*)d_in[4], (const float*)d_in[5],
        (const float*)d_in[6], (float*)d_out);
}